// Round 4
// baseline (543.458 us; speedup 1.0000x reference)
//
#include <hip/hip_runtime.h>
#include <stdint.h>

// Problem constants
#define BB    8
#define NN_   16384
#define SS    1024
#define PP    131072    // BB*NN_
#define CIN   512
#define CMID  256
#define COUT  256

typedef short  bf16x8 __attribute__((ext_vector_type(8)));
typedef float  f32x4  __attribute__((ext_vector_type(4)));
typedef unsigned short u16x8 __attribute__((ext_vector_type(8)));
typedef unsigned int uint_;

__device__ __forceinline__ float bf2f(unsigned short u){
  union { unsigned int i; float f; } v; v.i = ((unsigned int)u) << 16; return v.f;
}
__device__ __forceinline__ unsigned short f2bf(float f){
  union { float f; unsigned int i; } v; v.f = f;
  unsigned int r = (v.i + 0x7fffu + ((v.i >> 16) & 1u)) >> 16;  // RNE
  return (unsigned short)r;
}

// async global->LDS, 16B per lane; LDS dest must be wave-uniform base (+lane*16 implicit)
__device__ __forceinline__ void async_ld16(const void* g, void* l){
  const uint32_t __attribute__((address_space(1)))* gp =
    reinterpret_cast<const uint32_t __attribute__((address_space(1)))*>(reinterpret_cast<uintptr_t>(g));
  uint32_t __attribute__((address_space(3)))* lp =
    reinterpret_cast<uint32_t __attribute__((address_space(3)))*>(reinterpret_cast<uintptr_t>(l));
  __builtin_amdgcn_global_load_lds(gp, lp, 16, 0, 0);
}

// ---------------------------------------------------------------------------
// Prep: weights fp32->bf16, zero BN stats. (conv biases b0/b1 cancel exactly in
// training-mode BN: (y+b) - mean(y+b) == y - mean(y); variance unchanged.)
__global__ void k_prep(const float* __restrict__ w0, const float* __restrict__ w1,
                       unsigned short* __restrict__ w0b, unsigned short* __restrict__ w1b,
                       float* __restrict__ bn)
{
  int idx = blockIdx.x * 256 + threadIdx.x;   // grid 512 -> 131072 threads
  if (idx < 131072) w0b[idx] = f2bf(w0[idx]);
  if (idx < 65536)  w1b[idx] = f2bf(w1[idx]);
  if (idx < 2048)   bn[idx]  = 0.0f;          // stats + params region
}

// ---------------------------------------------------------------------------
// points2 [B][256][S] fp32 -> p2t [B][S][256] fp32 (coalesced gather rows)
__global__ void k_p2t(const float* __restrict__ p2, float* __restrict__ p2t)
{
  __shared__ float t[32][33];
  const int b = blockIdx.z, c0 = blockIdx.y * 32, s0 = blockIdx.x * 32;
  const int tx = threadIdx.x, ty = threadIdx.y;   // (32,8)
#pragma unroll
  for (int r = 0; r < 4; r++)
    t[ty + r*8][tx] = p2[((size_t)b*256 + c0 + ty + r*8) * SS + s0 + tx];
  __syncthreads();
#pragma unroll
  for (int r = 0; r < 4; r++)
    p2t[((size_t)b*SS + s0 + ty + r*8) * 256 + c0 + tx] = t[tx][ty + r*8];
}

// points1 [B][256][N] fp32 -> xcat[p][0:256] bf16  (row stride 512)
__global__ void k_p1t(const float* __restrict__ p1, unsigned short* __restrict__ xcat)
{
  __shared__ float t[32][33];
  const int b = blockIdx.z, c0 = blockIdx.y * 32, n0 = blockIdx.x * 32;
  const int tx = threadIdx.x, ty = threadIdx.y;
#pragma unroll
  for (int r = 0; r < 4; r++)
    t[ty + r*8][tx] = p1[((size_t)b*256 + c0 + ty + r*8) * (size_t)NN_ + n0 + tx];
  __syncthreads();
#pragma unroll
  for (int r = 0; r < 4; r++)
    xcat[((size_t)b*NN_ + n0 + ty + r*8) * 512 + c0 + tx] = f2bf(t[tx][ty + r*8]);
}

// ---------------------------------------------------------------------------
// 3-NN + inverse-distance interp -> xcat[p][256:512] bf16
// R8: scan was grid-limited (2 blocks/CU -> 2 waves/SIMD, VALUBusy 76% with
//     24% dep-stall idle). Split S-scan 2-threads-per-query: 1024 blocks x
//     128 queries; thread (tq, half) scans s in [half*512, half*512+512);
//     halves merged via LDS top-6 union (keys unique via index low-bits ->
//     set-union invariant, bit-identical final top-3). 4 waves/SIMD.
// R7: med3 network (float-domain keys), fp64 refine of 6 candidates.
__global__ __launch_bounds__(256) void k_nn(const float* __restrict__ xyz1,
                                            const float* __restrict__ xyz2,
                                            const float* __restrict__ p2t,
                                            unsigned short* __restrict__ xcat)
{
  __shared__ float4 pts[SS];       // 16 KB, broadcast reads
  __shared__ int4   mi[128];       // i0,i1,i2,pad per point
  __shared__ float4 mw[128];       // w0,w1,w2,pad per point
  __shared__ float  ck[128][6];    // half-1 partial top-6 keys
  const int blk = blockIdx.x;                  // 1024 blocks
  const int b = blk & 7, nt = blk >> 3;        // XCD-aware: b == XCD id
  const int n0 = nt * 128, tid = threadIdx.x;
  const int tq = tid & 127, half = tid >> 7;

  for (int s = tid; s < SS; s += 256) {
    float x = xyz2[((size_t)b*3 + 0) * SS + s];
    float y = xyz2[((size_t)b*3 + 1) * SS + s];
    float z = xyz2[((size_t)b*3 + 2) * SS + s];
    pts[s] = make_float4(x, y, z, 0.0f);
  }
  __syncthreads();

  const int n = n0 + tq;
  const float qx = xyz1[((size_t)b*3 + 0) * NN_ + n];
  const float qy = xyz1[((size_t)b*3 + 1) * NN_ + n];
  const float qz = xyz1[((size_t)b*3 + 2) * NN_ + n];

  // float-domain keys: key = bits((d & 0xFFFFFC00) | s). d >= 0 finite, so
  // float ordering == uint ordering; init FLT_MAX > any real key.
  const float KINIT = __uint_as_float(0x7F7FFFFFu);
  float c0 = KINIT, c1 = KINIT, c2 = KINIT, c3 = KINIT, c4 = KINIT, c5 = KINIT;
  const int s0 = half << 9;
#pragma unroll 4
  for (int s = s0; s < s0 + 512; s++) {
    float4 p = pts[s];
    float dx = qx - p.x, dy = qy - p.y, dz = qz - p.z;
    float d = fmaf(dx, dx, fmaf(dy, dy, dz * dz));
    float key = __uint_as_float((__float_as_uint(d) & 0xFFFFFC00u) | (uint_)s);
    // sorted-insert, all from OLD values: n0=min(c0,key), ni=med3(c_{i-1},ci,key)
    float m0 = fminf(c0, key);
    float m1 = __builtin_amdgcn_fmed3f(c0, c1, key);
    float m2 = __builtin_amdgcn_fmed3f(c1, c2, key);
    float m3 = __builtin_amdgcn_fmed3f(c2, c3, key);
    float m4 = __builtin_amdgcn_fmed3f(c3, c4, key);
    float m5 = __builtin_amdgcn_fmed3f(c4, c5, key);
    c0 = m0; c1 = m1; c2 = m2; c3 = m3; c4 = m4; c5 = m5;
  }

  if (half) {
    ck[tq][0] = c0; ck[tq][1] = c1; ck[tq][2] = c2;
    ck[tq][3] = c3; ck[tq][4] = c4; ck[tq][5] = c5;
  }
  __syncthreads();

  if (!half) {
    // merge foreign top-6 into local network (sorted-insert preserves order)
#pragma unroll
    for (int j = 0; j < 6; j++) {
      float key = ck[tq][j];
      float m0 = fminf(c0, key);
      float m1 = __builtin_amdgcn_fmed3f(c0, c1, key);
      float m2 = __builtin_amdgcn_fmed3f(c1, c2, key);
      float m3 = __builtin_amdgcn_fmed3f(c2, c3, key);
      float m4 = __builtin_amdgcn_fmed3f(c3, c4, key);
      float m5 = __builtin_amdgcn_fmed3f(c4, c5, key);
      c0 = m0; c1 = m1; c2 = m2; c3 = m3; c4 = m4; c5 = m5;
    }

    // fp64 refine: exact distances for the 6 candidates, stable sort, top-3
    const double qxd = (double)qx, qyd = (double)qy, qzd = (double)qz;
    uint_  ks[6] = { __float_as_uint(c0), __float_as_uint(c1), __float_as_uint(c2),
                     __float_as_uint(c3), __float_as_uint(c4), __float_as_uint(c5) };
    int    ii[6];
    double dd[6];
#pragma unroll
    for (int t = 0; t < 6; t++) {
      ii[t] = (int)(ks[t] & 1023u);
      float4 p = pts[ii[t]];
      double dx = qxd - (double)p.x, dy = qyd - (double)p.y, dz = qzd - (double)p.z;
      dd[t] = dx*dx + dy*dy + dz*dz;
    }
#pragma unroll
    for (int a = 1; a < 6; a++)
#pragma unroll
      for (int c = a; c > 0; c--)
        if (dd[c] < dd[c-1]) {
          double td = dd[c]; dd[c] = dd[c-1]; dd[c-1] = td;
          int    ti = ii[c]; ii[c] = ii[c-1]; ii[c-1] = ti;
        }

    double r0 = 1.0/(dd[0] + 1e-8), r1 = 1.0/(dd[1] + 1e-8), r2 = 1.0/(dd[2] + 1e-8);
    double rs = 1.0/(r0 + r1 + r2);
    mi[tq] = make_int4(ii[0], ii[1], ii[2], 0);
    mw[tq] = make_float4((float)(r0*rs), (float)(r1*rs), (float)(r2*rs), 0.0f);
  }
  __syncthreads();

  // gather: wave w interpolates points j in [w*32, w*32+32); lane covers 4 ch
  const int wid = tid >> 6, lane = tid & 63;
  const float* p2tb = p2t + (size_t)b * SS * 256;
  unsigned short* outb = xcat + ((size_t)b*NN_ + n0) * 512 + 256 + lane*4;
#pragma unroll 2
  for (int t = 0; t < 32; t++) {
    int j = wid*32 + t;
    int4   im = mi[j];                 // broadcast ds_read_b128
    float4 wm = mw[j];
    const float4* ra = (const float4*)(p2tb + (size_t)im.x * 256) + lane;
    const float4* rb = (const float4*)(p2tb + (size_t)im.y * 256) + lane;
    const float4* rc = (const float4*)(p2tb + (size_t)im.z * 256) + lane;
    float4 A = *ra, Bv = *rb, Cv = *rc;
    float fx = wm.x*A.x + wm.y*Bv.x + wm.z*Cv.x;
    float fy = wm.x*A.y + wm.y*Bv.y + wm.z*Cv.y;
    float fz = wm.x*A.z + wm.y*Bv.z + wm.z*Cv.z;
    float fw = wm.x*A.w + wm.y*Bv.w + wm.z*Cv.w;
    uint_ lo = (uint_)f2bf(fx) | ((uint_)f2bf(fy) << 16);
    uint_ hi = (uint_)f2bf(fz) | ((uint_)f2bf(fw) << 16);
    uint2 pk; pk.x = lo; pk.y = hi;
    *(uint2*)(outb + (size_t)j * 512) = pk;
  }
}

// ---------------------------------------------------------------------------
// NT GEMM: Y[p][o] = sum_c X[p][c]*W[o][c].  X:[P][K] bf16, W:[256][K] bf16.
// R8: R6's 8-wave/128-VGPR-acc config was VGPR-capped at 2 waves/SIMD and
//     1 block/CU -> nothing filled the staging stalls. Same 256x256 tile,
//     now 16 waves of 64x64 (acc[4][4]=64 VGPR, total ~116) ->
//     __launch_bounds__(1024,4) = 4 waves/SIMD at the same 4x32KB pipeline.
//     BK=32, stage(t+3) 3-deep prefetch, counted vmcnt (never 0 mid-loop).
//     LDS swizzle: slot ^= (row>>1)&3 on global source addr + ds_read addr.
// Epilogue: per-channel sum/sumsq atomics (BN stats) + bf16 store.
__global__ __launch_bounds__(1024, 4) void k_gemm(const unsigned short* __restrict__ X,
                                                  const unsigned short* __restrict__ W,
                                                  unsigned short* __restrict__ Y,
                                                  float* __restrict__ bnsum,
                                                  float* __restrict__ bnsumsq,
                                                  int K)
{
  extern __shared__ char smem[];   // 4 bufs x 32KB: [A 16KB | B 16KB]
  const int tid  = threadIdx.x;
  const int wid  = tid >> 6, lane = tid & 63;
  const int quad = lane >> 4, l16 = lane & 15;
  const int wp = wid >> 2, wo = wid & 3;          // 4 p-waves x 4 o-waves
  const size_t p0 = (size_t)blockIdx.x * 256;

  f32x4 acc[4][4] = {};   // 64 VGPR

  // staging: per buffer A = 16KB = 1024 granules of 16B; thread stages granule tid
  // row = tid>>2 (0..255), slot = tid&3; swizzled source chunk = slot ^ ((row>>1)&3)
  const int grow = tid >> 2;
  const int gcol = (((tid & 3) ^ ((tid >> 3) & 3)) << 3);   // elems (0,8,16,24)
  const unsigned short* gA = X + (p0 + grow) * (size_t)K + gcol;
  const unsigned short* gB = W + (size_t)grow * K + gcol;
  const int ldw = wid << 10;   // wave-uniform byte offset (64 granules x 16B)

  auto stage = [&](int t) {
    char* base = smem + ((t & 3) << 15);
    const int kk = t << 5;
    async_ld16(gA + kk, base + ldw);
    async_ld16(gB + kk, base + 16384 + ldw);
  };

  // frag-read offsets (within a buffer region), swizzled slot
  const int sw   = (quad ^ ((l16 >> 1) & 3)) << 4;
  const int aoff = ((wp << 6) + l16) * 64 + sw;   // + m*1024
  const int boff = ((wo << 6) + l16) * 64 + sw;   // + n*1024

  const int nt = K >> 5;
  stage(0); stage(1); stage(2);
  asm volatile("s_waitcnt vmcnt(4)" ::: "memory");   // buf0 landed (1,2 in flight)
  __builtin_amdgcn_s_barrier();

  for (int t = 0; t < nt; ++t) {
    const char* buf = smem + ((t & 3) << 15);
    bf16x8 af[4], bfr[4];
#pragma unroll
    for (int m = 0; m < 4; m++) af[m]  = *(const bf16x8*)(buf + aoff + m*1024);
#pragma unroll
    for (int n = 0; n < 4; n++) bfr[n] = *(const bf16x8*)(buf + 16384 + boff + n*1024);
    asm volatile("s_waitcnt lgkmcnt(0)" ::: "memory");  // my frags in regs
    __builtin_amdgcn_s_barrier();                       // all waves done reading <= buf t
    if (t + 3 < nt) stage(t + 3);                       // overwrites buf[(t-1)&3], safe
#pragma unroll
    for (int m = 0; m < 4; m++)
#pragma unroll
      for (int n = 0; n < 4; n++)
        acc[m][n] = __builtin_amdgcn_mfma_f32_16x16x32_bf16(af[m], bfr[n], acc[m][n], 0, 0, 0);
    if (t < nt - 1) {
      if (t + 3 < nt)      asm volatile("s_waitcnt vmcnt(4)" ::: "memory");  // t+1 landed
      else if (t + 2 < nt) asm volatile("s_waitcnt vmcnt(2)" ::: "memory");
      else                 asm volatile("s_waitcnt vmcnt(0)" ::: "memory");
      __builtin_amdgcn_s_barrier();
    }
  }

  // BN stats: lane sums its 16 rows (4m x 4i), reduce across quads, atomic per o
#pragma unroll
  for (int n = 0; n < 4; n++) {
    float s = 0.0f, ss = 0.0f;
#pragma unroll
    for (int m = 0; m < 4; m++)
#pragma unroll
      for (int i = 0; i < 4; i++) { float v = acc[m][n][i]; s += v; ss += v*v; }
    s  += __shfl_xor(s, 16, 64);  s  += __shfl_xor(s, 32, 64);
    ss += __shfl_xor(ss, 16, 64); ss += __shfl_xor(ss, 32, 64);
    if (quad == 0) {
      int o = (wo << 6) + (n << 4) + l16;
      atomicAdd(&bnsum[o], s);
      atomicAdd(&bnsumsq[o], ss);
    }
  }
  // store raw y (bf16). D: row(p)=quad*4+i, col(o)=l16
#pragma unroll
  for (int m = 0; m < 4; m++)
#pragma unroll
    for (int n = 0; n < 4; n++)
#pragma unroll
      for (int i = 0; i < 4; i++) {
        size_t p = p0 + (wp << 6) + (m << 4) + (quad << 2) + i;
        int    o = (wo << 6) + (n << 4) + l16;
        Y[p * 256 + o] = f2bf(acc[m][n][i]);
      }
}

// ---------------------------------------------------------------------------
// BN param: scale = g*rsqrt(var+eps), shift = be - mean*scale
__global__ void k_bn(const float* __restrict__ sum, const float* __restrict__ sumsq,
                     const float* __restrict__ g, const float* __restrict__ be,
                     float* __restrict__ scale, float* __restrict__ shift)
{
  int o = threadIdx.x;
  const float inv = 1.0f / 131072.0f;
  float m  = sum[o] * inv;
  float v  = sumsq[o] * inv - m * m;
  float sc = g[o] * rsqrtf(v + 1e-5f);
  scale[o] = sc;
  shift[o] = be[o] - m * sc;
}

// elementwise z = relu(y*scale + shift), bf16 -> bf16 (keeps GEMM2 stage-able via lds-direct)
__global__ __launch_bounds__(256) void k_z(const unsigned short* __restrict__ y,
                                           const float* __restrict__ scale,
                                           const float* __restrict__ shift,
                                           unsigned short* __restrict__ z)
{
  size_t idx = ((size_t)blockIdx.x * 256 + threadIdx.x) * 8;
  int o = (int)(idx & 255);
  u16x8 v = *(const u16x8*)(y + idx);
  u16x8 r;
#pragma unroll
  for (int i = 0; i < 8; i++) {
    float f = bf2f(v[i]);
    float t = f * scale[o + i] + shift[o + i];
    r[i] = f2bf(fmaxf(t, 0.0f));
  }
  *(u16x8*)(z + idx) = r;
}

// final: y1[p][o] bf16 -> out[b][o][n] fp32 with BN+relu, LDS transpose
__global__ __launch_bounds__(256) void k_out(const unsigned short* __restrict__ y1,
                                             const float* __restrict__ scale,
                                             const float* __restrict__ shift,
                                             float* __restrict__ out)
{
  __shared__ float t[64][65];
  const int b = blockIdx.z, o0 = blockIdx.y * 64, n0 = blockIdx.x * 64;
  const int tx = threadIdx.x & 15, ty = threadIdx.x >> 4;
  const float4 sc = *(const float4*)(scale + o0 + tx*4);
  const float4 sh = *(const float4*)(shift + o0 + tx*4);
#pragma unroll
  for (int r = 0; r < 4; r++) {
    int nl = ty + r*16;
    const unsigned short* src = y1 + ((size_t)b*NN_ + n0 + nl) * 256 + o0 + tx*4;
    ushort4 v = *(const ushort4*)src;
    t[tx*4+0][nl] = fmaxf(bf2f(v.x) * sc.x + sh.x, 0.0f);
    t[tx*4+1][nl] = fmaxf(bf2f(v.y) * sc.y + sh.y, 0.0f);
    t[tx*4+2][nl] = fmaxf(bf2f(v.z) * sc.z + sh.z, 0.0f);
    t[tx*4+3][nl] = fmaxf(bf2f(v.w) * sc.w + sh.w, 0.0f);
  }
  __syncthreads();
#pragma unroll
  for (int r = 0; r < 4; r++) {
    int ol = ty + r*16;
    float4 o4 = make_float4(t[ol][tx*4+0], t[ol][tx*4+1], t[ol][tx*4+2], t[ol][tx*4+3]);
    *(float4*)(out + ((size_t)b*256 + o0 + ol) * (size_t)NN_ + n0 + tx*4) = o4;
  }
}

// ---------------------------------------------------------------------------
extern "C" void kernel_launch(void* const* d_in, const int* in_sizes, int n_in,
                              void* d_out, int out_size, void* d_ws, size_t ws_size,
                              hipStream_t stream)
{
  const float* xyz1 = (const float*)d_in[0];
  const float* xyz2 = (const float*)d_in[1];
  const float* p1   = (const float*)d_in[2];
  const float* p2   = (const float*)d_in[3];
  const float* w0   = (const float*)d_in[4];
  const float* g0   = (const float*)d_in[6];
  const float* be0  = (const float*)d_in[7];
  const float* w1   = (const float*)d_in[8];
  const float* g1   = (const float*)d_in[10];
  const float* be1  = (const float*)d_in[11];

  // workspace layout (~192.5 MiB):
  //   [0,128Mi)    xcat [P][512] bf16      (later reused: z=[0,64Mi), y1=[64Mi,128Mi))
  //   [128,192Mi)  y0 [P][256] bf16        (p2t aliases its first 8 MiB; dead before gemm1 writes)
  //   [192Mi,...]  w0b, w1b, bn stats/params
  char* ws = (char*)d_ws;
  unsigned short* xcat = (unsigned short*)(ws);
  unsigned short* y0   = (unsigned short*)(ws + 134217728ull);
  unsigned short* zbuf = (unsigned short*)(ws);
  unsigned short* y1   = (unsigned short*)(ws + 67108864ull);
  float*          p2t  = (float*)        (ws + 134217728ull);
  unsigned short* w0b  = (unsigned short*)(ws + 201326592ull);
  unsigned short* w1b  = (unsigned short*)(ws + 201588736ull);
  float*          bn   = (float*)        (ws + 201719808ull);
  // bn: [0]sum0 [256]sumsq0 [512]sum1 [768]sumsq1 [1024]scale0 [1280]shift0 [1536]scale1 [1792]shift1

  static bool s_init = false;
  if (!s_init) {
    hipFuncSetAttribute(reinterpret_cast<const void*>(&k_gemm),
                        hipFuncAttributeMaxDynamicSharedMemorySize, 131072);
    s_init = true;
  }

  k_prep<<<512, 256, 0, stream>>>(w0, w1, w0b, w1b, bn);
  k_p2t <<<dim3(32, 8, 8),  dim3(32, 8), 0, stream>>>(p2, p2t);
  k_p1t <<<dim3(512, 8, 8), dim3(32, 8), 0, stream>>>(p1, xcat);
  k_nn  <<<1024, 256, 0, stream>>>(xyz1, xyz2, p2t, xcat);
  k_gemm<<<512, 1024, 131072, stream>>>(xcat, w0b, y0, bn + 0,   bn + 256, 512);
  k_bn  <<<1, 256, 0, stream>>>(bn + 0,   bn + 256, g0, be0, bn + 1024, bn + 1280);
  k_z   <<<16384, 256, 0, stream>>>(y0, bn + 1024, bn + 1280, zbuf);
  k_gemm<<<512, 1024, 131072, stream>>>(zbuf, w1b, y1, bn + 512, bn + 768, 256);
  k_bn  <<<1, 256, 0, stream>>>(bn + 512, bn + 768, g1, be1, bn + 1536, bn + 1792);
  k_out <<<dim3(256, 4, 8), 256, 0, stream>>>(y1, bn + 1536, bn + 1792, (float*)d_out);
}

// Round 5
// 505.747 us; speedup vs baseline: 1.0746x; 1.0746x over previous
//
#include <hip/hip_runtime.h>
#include <stdint.h>

// Problem constants
#define BB    8
#define NN_   16384
#define SS    1024
#define PP    131072    // BB*NN_
#define CIN   512
#define CMID  256
#define COUT  256

typedef short  bf16x8 __attribute__((ext_vector_type(8)));
typedef float  f32x4  __attribute__((ext_vector_type(4)));
typedef unsigned short u16x8 __attribute__((ext_vector_type(8)));
typedef unsigned int uint_;

__device__ __forceinline__ float bf2f(unsigned short u){
  union { unsigned int i; float f; } v; v.i = ((unsigned int)u) << 16; return v.f;
}
__device__ __forceinline__ unsigned short f2bf(float f){
  union { float f; unsigned int i; } v; v.f = f;
  unsigned int r = (v.i + 0x7fffu + ((v.i >> 16) & 1u)) >> 16;  // RNE
  return (unsigned short)r;
}

// async global->LDS, 16B per lane; LDS dest must be wave-uniform base (+lane*16 implicit)
__device__ __forceinline__ void async_ld16(const void* g, void* l){
  const uint32_t __attribute__((address_space(1)))* gp =
    reinterpret_cast<const uint32_t __attribute__((address_space(1)))*>(reinterpret_cast<uintptr_t>(g));
  uint32_t __attribute__((address_space(3)))* lp =
    reinterpret_cast<uint32_t __attribute__((address_space(3)))*>(reinterpret_cast<uintptr_t>(l));
  __builtin_amdgcn_global_load_lds(gp, lp, 16, 0, 0);
}

// ---------------------------------------------------------------------------
// Prep: weights fp32->bf16, zero BN stats. (conv biases b0/b1 cancel exactly in
// training-mode BN: (y+b) - mean(y+b) == y - mean(y); variance unchanged.)
__global__ void k_prep(const float* __restrict__ w0, const float* __restrict__ w1,
                       unsigned short* __restrict__ w0b, unsigned short* __restrict__ w1b,
                       float* __restrict__ bn)
{
  int idx = blockIdx.x * 256 + threadIdx.x;   // grid 512 -> 131072 threads
  if (idx < 131072) w0b[idx] = f2bf(w0[idx]);
  if (idx < 65536)  w1b[idx] = f2bf(w1[idx]);
  if (idx < 2048)   bn[idx]  = 0.0f;          // stats + params region
}

// ---------------------------------------------------------------------------
// points2 [B][256][S] fp32 -> p2t [B][S][256] fp32 (coalesced gather rows)
__global__ void k_p2t(const float* __restrict__ p2, float* __restrict__ p2t)
{
  __shared__ float t[32][33];
  const int b = blockIdx.z, c0 = blockIdx.y * 32, s0 = blockIdx.x * 32;
  const int tx = threadIdx.x, ty = threadIdx.y;   // (32,8)
#pragma unroll
  for (int r = 0; r < 4; r++)
    t[ty + r*8][tx] = p2[((size_t)b*256 + c0 + ty + r*8) * SS + s0 + tx];
  __syncthreads();
#pragma unroll
  for (int r = 0; r < 4; r++)
    p2t[((size_t)b*SS + s0 + ty + r*8) * 256 + c0 + tx] = t[tx][ty + r*8];
}

// points1 [B][256][N] fp32 -> xcat[p][0:256] bf16  (row stride 512)
__global__ void k_p1t(const float* __restrict__ p1, unsigned short* __restrict__ xcat)
{
  __shared__ float t[32][33];
  const int b = blockIdx.z, c0 = blockIdx.y * 32, n0 = blockIdx.x * 32;
  const int tx = threadIdx.x, ty = threadIdx.y;
#pragma unroll
  for (int r = 0; r < 4; r++)
    t[ty + r*8][tx] = p1[((size_t)b*256 + c0 + ty + r*8) * (size_t)NN_ + n0 + tx];
  __syncthreads();
#pragma unroll
  for (int r = 0; r < 4; r++)
    xcat[((size_t)b*NN_ + n0 + ty + r*8) * 512 + c0 + tx] = f2bf(t[tx][ty + r*8]);
}

// ---------------------------------------------------------------------------
// 3-NN + inverse-distance interp -> xcat[p][256:512] bf16
// R9: reverted to the R7 version (measured 85.6 us); R8's 2-thread-split was
//     an unmeasured variable. Changes this round are k_gemm-only.
// R7: med3 network (float-domain keys), fp64 refine of 6 candidates.
__global__ __launch_bounds__(256) void k_nn(const float* __restrict__ xyz1,
                                            const float* __restrict__ xyz2,
                                            const float* __restrict__ p2t,
                                            unsigned short* __restrict__ xcat)
{
  __shared__ float4 pts[SS];       // 16 KB, broadcast reads
  __shared__ int4   mi[256];       // 4 KB: i0,i1,i2,pad per point
  __shared__ float4 mw[256];       // 4 KB: w0,w1,w2,pad per point
  const int blk = blockIdx.x;                  // 512 blocks
  const int b = blk & 7, nt = blk >> 3;        // XCD-aware: b == XCD id
  const int n0 = nt * 256, tid = threadIdx.x;

  for (int s = tid; s < SS; s += 256) {
    float x = xyz2[((size_t)b*3 + 0) * SS + s];
    float y = xyz2[((size_t)b*3 + 1) * SS + s];
    float z = xyz2[((size_t)b*3 + 2) * SS + s];
    pts[s] = make_float4(x, y, z, 0.0f);
  }
  __syncthreads();

  const int n = n0 + tid;
  const float qx = xyz1[((size_t)b*3 + 0) * NN_ + n];
  const float qy = xyz1[((size_t)b*3 + 1) * NN_ + n];
  const float qz = xyz1[((size_t)b*3 + 2) * NN_ + n];

  // float-domain keys: key = bits((d & 0xFFFFFC00) | s). d >= 0 finite, so
  // float ordering == uint ordering; init FLT_MAX > any real key.
  const float KINIT = __uint_as_float(0x7F7FFFFFu);
  float c0 = KINIT, c1 = KINIT, c2 = KINIT, c3 = KINIT, c4 = KINIT, c5 = KINIT;
#pragma unroll 4
  for (int s = 0; s < SS; s++) {
    float4 p = pts[s];
    float dx = qx - p.x, dy = qy - p.y, dz = qz - p.z;
    float d = fmaf(dx, dx, fmaf(dy, dy, dz * dz));
    float key = __uint_as_float((__float_as_uint(d) & 0xFFFFFC00u) | (uint_)s);
    // sorted-insert, all from OLD values: n0=min(c0,key), ni=med3(c_{i-1},ci,key)
    float m0 = fminf(c0, key);
    float m1 = __builtin_amdgcn_fmed3f(c0, c1, key);
    float m2 = __builtin_amdgcn_fmed3f(c1, c2, key);
    float m3 = __builtin_amdgcn_fmed3f(c2, c3, key);
    float m4 = __builtin_amdgcn_fmed3f(c3, c4, key);
    float m5 = __builtin_amdgcn_fmed3f(c4, c5, key);
    c0 = m0; c1 = m1; c2 = m2; c3 = m3; c4 = m4; c5 = m5;
  }

  // fp64 refine: exact distances for the 6 candidates, stable sort, top-3
  const double qxd = (double)qx, qyd = (double)qy, qzd = (double)qz;
  uint_  ks[6] = { __float_as_uint(c0), __float_as_uint(c1), __float_as_uint(c2),
                   __float_as_uint(c3), __float_as_uint(c4), __float_as_uint(c5) };
  int    ii[6];
  double dd[6];
#pragma unroll
  for (int t = 0; t < 6; t++) {
    ii[t] = (int)(ks[t] & 1023u);
    float4 p = pts[ii[t]];
    double dx = qxd - (double)p.x, dy = qyd - (double)p.y, dz = qzd - (double)p.z;
    dd[t] = dx*dx + dy*dy + dz*dz;
  }
#pragma unroll
  for (int a = 1; a < 6; a++)
#pragma unroll
    for (int c = a; c > 0; c--)
      if (dd[c] < dd[c-1]) {
        double td = dd[c]; dd[c] = dd[c-1]; dd[c-1] = td;
        int    ti = ii[c]; ii[c] = ii[c-1]; ii[c-1] = ti;
      }

  double r0 = 1.0/(dd[0] + 1e-8), r1 = 1.0/(dd[1] + 1e-8), r2 = 1.0/(dd[2] + 1e-8);
  double rs = 1.0/(r0 + r1 + r2);
  mi[tid] = make_int4(ii[0], ii[1], ii[2], 0);
  mw[tid] = make_float4((float)(r0*rs), (float)(r1*rs), (float)(r2*rs), 0.0f);
  __syncthreads();

  const int wid = tid >> 6, lane = tid & 63;
  const float* p2tb = p2t + (size_t)b * SS * 256;
  unsigned short* outb = xcat + ((size_t)b*NN_ + n0) * 512 + 256 + lane*4;
#pragma unroll 2
  for (int t = 0; t < 64; t++) {
    int j = wid*64 + t;
    int4   im = mi[j];                 // broadcast ds_read_b128
    float4 wm = mw[j];
    const float4* ra = (const float4*)(p2tb + (size_t)im.x * 256) + lane;
    const float4* rb = (const float4*)(p2tb + (size_t)im.y * 256) + lane;
    const float4* rc = (const float4*)(p2tb + (size_t)im.z * 256) + lane;
    float4 A = *ra, Bv = *rb, Cv = *rc;
    float fx = wm.x*A.x + wm.y*Bv.x + wm.z*Cv.x;
    float fy = wm.x*A.y + wm.y*Bv.y + wm.z*Cv.y;
    float fz = wm.x*A.z + wm.y*Bv.z + wm.z*Cv.z;
    float fw = wm.x*A.w + wm.y*Bv.w + wm.z*Cv.w;
    uint_ lo = (uint_)f2bf(fx) | ((uint_)f2bf(fy) << 16);
    uint_ hi = (uint_)f2bf(fz) | ((uint_)f2bf(fw) << 16);
    uint2 pk; pk.x = lo; pk.y = hi;
    *(uint2*)(outb + (size_t)j * 512) = pk;
  }
}

// ---------------------------------------------------------------------------
// NT GEMM: Y[p][o] = sum_c X[p][c]*W[o][c].  X:[P][K] bf16, W:[256][K] bf16.
// R9: R6 geometry (256x256 tile, 8 waves of 128x64, BK=32, 4 LDS buffers,
//     counted vmcnt) with the sync structure thinned:
//     - ONE barrier per K-step. With >=3 buffers the pre-stage barrier is
//       redundant: wave B's reads of buf[(t-1)&3] completed (its own lgkmcnt
//       before MFMA) before the end-of-step-(t-1) barrier, and stage(t+3)
//       (the only writer of that buffer) is issued after that barrier.
//     - stage(t+3) issued FIRST in the step (issue-early, T14): HBM latency
//       hides under ds_read + 32 MFMA.
//     - s_setprio(1/0) around the MFMA cluster (T5).
//     - compiler-scheduled lgkmcnt for ds_read->MFMA (no asm lgkm drain).
//     R8 lesson: 16 waves of 64x64 regressed (shorter MFMA bursts, 2x barrier
//     participants) -> wave-depth beats wave-count here.
// Epilogue: per-channel sum/sumsq atomics (BN stats) + bf16 store.
__global__ __launch_bounds__(512, 2) void k_gemm(const unsigned short* __restrict__ X,
                                                 const unsigned short* __restrict__ W,
                                                 unsigned short* __restrict__ Y,
                                                 float* __restrict__ bnsum,
                                                 float* __restrict__ bnsumsq,
                                                 int K)
{
  extern __shared__ char smem[];   // 4 bufs x 32KB: [A 16KB | B 16KB]
  const int tid  = threadIdx.x;
  const int wid  = tid >> 6, lane = tid & 63;
  const int quad = lane >> 4, l16 = lane & 15;
  const int wp = wid >> 2, wo = wid & 3;          // 2 p-waves x 4 o-waves
  const size_t p0 = (size_t)blockIdx.x * 256;

  f32x4 acc[8][4] = {};   // 128 regs (AGPR side of unified file)

  // --- staging map: per buffer A = 1024 granules of 16B (256 rows x 4 slots)
  const int grow = (wid << 4) | (lane >> 2);
  const int gcol = (((lane & 3) ^ ((lane >> 3) & 3)) << 3);   // elems (0,8,16,24)
  const unsigned short* gA0 = X + (p0 + grow)       * (size_t)K + gcol;
  const unsigned short* gA1 = X + (p0 + grow + 128) * (size_t)K + gcol;
  const unsigned short* gB0 = W + (size_t)(grow)       * K + gcol;
  const unsigned short* gB1 = W + (size_t)(grow + 128) * K + gcol;
  const int ldw = wid << 10;   // wid*1024 bytes (64 granules)

  auto stage = [&](int t) {
    char* base = smem + ((t & 3) << 15);
    const int kk = t << 5;
    async_ld16(gA0 + kk, base + ldw);
    async_ld16(gA1 + kk, base + 8192 + ldw);
    async_ld16(gB0 + kk, base + 16384 + ldw);
    async_ld16(gB1 + kk, base + 16384 + 8192 + ldw);
  };

  // --- frag-read offsets (within a buffer region), swizzled slot
  const int sw   = (quad ^ ((l16 >> 1) & 3)) << 4;
  const int aoff = ((wp << 7) + l16) * 64 + sw;   // + m*1024
  const int boff = ((wo << 6) + l16) * 64 + sw;   // + n*1024

  const int nt = K >> 5;
  stage(0); stage(1); stage(2);
  asm volatile("s_waitcnt vmcnt(8)" ::: "memory");   // buf0 landed (1,2 in flight)
  __builtin_amdgcn_s_barrier();

  for (int t = 0; t < nt; ++t) {
    if (t + 3 < nt) stage(t + 3);      // issue-early; writes buf[(t-1)&3], safe
    const char* buf = smem + ((t & 3) << 15);
    bf16x8 af[8], bfr[4];
#pragma unroll
    for (int m = 0; m < 8; m++) af[m]  = *(const bf16x8*)(buf + aoff + m*1024);
#pragma unroll
    for (int n = 0; n < 4; n++) bfr[n] = *(const bf16x8*)(buf + 16384 + boff + n*1024);
    __builtin_amdgcn_s_setprio(1);
#pragma unroll
    for (int m = 0; m < 8; m++)
#pragma unroll
      for (int n = 0; n < 4; n++)
        acc[m][n] = __builtin_amdgcn_mfma_f32_16x16x32_bf16(af[m], bfr[n], acc[m][n], 0, 0, 0);
    __builtin_amdgcn_s_setprio(0);
    if (t < nt - 1) {
      // wait tile t+1 landed; outstanding beyond it stays in flight
      if (t + 3 < nt)       asm volatile("s_waitcnt vmcnt(8)" ::: "memory");
      else if (t + 3 == nt) asm volatile("s_waitcnt vmcnt(4)" ::: "memory");
      else                  asm volatile("s_waitcnt vmcnt(0)" ::: "memory");
      __builtin_amdgcn_s_barrier();
    }
  }

  // BN stats: lane sums its 32 rows (8m x 4i), reduce across quads, atomic per o
#pragma unroll
  for (int n = 0; n < 4; n++) {
    float s = 0.0f, ss = 0.0f;
#pragma unroll
    for (int m = 0; m < 8; m++)
#pragma unroll
      for (int i = 0; i < 4; i++) { float v = acc[m][n][i]; s += v; ss += v*v; }
    s  += __shfl_xor(s, 16, 64);  s  += __shfl_xor(s, 32, 64);
    ss += __shfl_xor(ss, 16, 64); ss += __shfl_xor(ss, 32, 64);
    if (quad == 0) {
      int o = (wo << 6) + (n << 4) + l16;
      atomicAdd(&bnsum[o], s);
      atomicAdd(&bnsumsq[o], ss);
    }
  }
  // store raw y (bf16). D: row(p)=quad*4+i, col(o)=l16
#pragma unroll
  for (int m = 0; m < 8; m++)
#pragma unroll
    for (int n = 0; n < 4; n++)
#pragma unroll
      for (int i = 0; i < 4; i++) {
        size_t p = p0 + (wp << 7) + (m << 4) + (quad << 2) + i;
        int    o = (wo << 6) + (n << 4) + l16;
        Y[p * 256 + o] = f2bf(acc[m][n][i]);
      }
}

// ---------------------------------------------------------------------------
// BN param: scale = g*rsqrt(var+eps), shift = be - mean*scale
__global__ void k_bn(const float* __restrict__ sum, const float* __restrict__ sumsq,
                     const float* __restrict__ g, const float* __restrict__ be,
                     float* __restrict__ scale, float* __restrict__ shift)
{
  int o = threadIdx.x;
  const float inv = 1.0f / 131072.0f;
  float m  = sum[o] * inv;
  float v  = sumsq[o] * inv - m * m;
  float sc = g[o] * rsqrtf(v + 1e-5f);
  scale[o] = sc;
  shift[o] = be[o] - m * sc;
}

// elementwise z = relu(y*scale + shift), bf16 -> bf16 (keeps GEMM2 stage-able via lds-direct)
__global__ __launch_bounds__(256) void k_z(const unsigned short* __restrict__ y,
                                           const float* __restrict__ scale,
                                           const float* __restrict__ shift,
                                           unsigned short* __restrict__ z)
{
  size_t idx = ((size_t)blockIdx.x * 256 + threadIdx.x) * 8;
  int o = (int)(idx & 255);
  u16x8 v = *(const u16x8*)(y + idx);
  u16x8 r;
#pragma unroll
  for (int i = 0; i < 8; i++) {
    float f = bf2f(v[i]);
    float t = f * scale[o + i] + shift[o + i];
    r[i] = f2bf(fmaxf(t, 0.0f));
  }
  *(u16x8*)(z + idx) = r;
}

// final: y1[p][o] bf16 -> out[b][o][n] fp32 with BN+relu, LDS transpose
__global__ __launch_bounds__(256) void k_out(const unsigned short* __restrict__ y1,
                                             const float* __restrict__ scale,
                                             const float* __restrict__ shift,
                                             float* __restrict__ out)
{
  __shared__ float t[64][65];
  const int b = blockIdx.z, o0 = blockIdx.y * 64, n0 = blockIdx.x * 64;
  const int tx = threadIdx.x & 15, ty = threadIdx.x >> 4;
  const float4 sc = *(const float4*)(scale + o0 + tx*4);
  const float4 sh = *(const float4*)(shift + o0 + tx*4);
#pragma unroll
  for (int r = 0; r < 4; r++) {
    int nl = ty + r*16;
    const unsigned short* src = y1 + ((size_t)b*NN_ + n0 + nl) * 256 + o0 + tx*4;
    ushort4 v = *(const ushort4*)src;
    t[tx*4+0][nl] = fmaxf(bf2f(v.x) * sc.x + sh.x, 0.0f);
    t[tx*4+1][nl] = fmaxf(bf2f(v.y) * sc.y + sh.y, 0.0f);
    t[tx*4+2][nl] = fmaxf(bf2f(v.z) * sc.z + sh.z, 0.0f);
    t[tx*4+3][nl] = fmaxf(bf2f(v.w) * sc.w + sh.w, 0.0f);
  }
  __syncthreads();
#pragma unroll
  for (int r = 0; r < 4; r++) {
    int ol = ty + r*16;
    float4 o4 = make_float4(t[ol][tx*4+0], t[ol][tx*4+1], t[ol][tx*4+2], t[ol][tx*4+3]);
    *(float4*)(out + ((size_t)b*256 + o0 + ol) * (size_t)NN_ + n0 + tx*4) = o4;
  }
}

// ---------------------------------------------------------------------------
extern "C" void kernel_launch(void* const* d_in, const int* in_sizes, int n_in,
                              void* d_out, int out_size, void* d_ws, size_t ws_size,
                              hipStream_t stream)
{
  const float* xyz1 = (const float*)d_in[0];
  const float* xyz2 = (const float*)d_in[1];
  const float* p1   = (const float*)d_in[2];
  const float* p2   = (const float*)d_in[3];
  const float* w0   = (const float*)d_in[4];
  const float* g0   = (const float*)d_in[6];
  const float* be0  = (const float*)d_in[7];
  const float* w1   = (const float*)d_in[8];
  const float* g1   = (const float*)d_in[10];
  const float* be1  = (const float*)d_in[11];

  // workspace layout (~192.5 MiB):
  //   [0,128Mi)    xcat [P][512] bf16      (later reused: z=[0,64Mi), y1=[64Mi,128Mi))
  //   [128,192Mi)  y0 [P][256] bf16        (p2t aliases its first 8 MiB; dead before gemm1 writes)
  //   [192Mi,...]  w0b, w1b, bn stats/params
  char* ws = (char*)d_ws;
  unsigned short* xcat = (unsigned short*)(ws);
  unsigned short* y0   = (unsigned short*)(ws + 134217728ull);
  unsigned short* zbuf = (unsigned short*)(ws);
  unsigned short* y1   = (unsigned short*)(ws + 67108864ull);
  float*          p2t  = (float*)        (ws + 134217728ull);
  unsigned short* w0b  = (unsigned short*)(ws + 201326592ull);
  unsigned short* w1b  = (unsigned short*)(ws + 201588736ull);
  float*          bn   = (float*)        (ws + 201719808ull);
  // bn: [0]sum0 [256]sumsq0 [512]sum1 [768]sumsq1 [1024]scale0 [1280]shift0 [1536]scale1 [1792]shift1

  static bool s_init = false;
  if (!s_init) {
    hipFuncSetAttribute(reinterpret_cast<const void*>(&k_gemm),
                        hipFuncAttributeMaxDynamicSharedMemorySize, 131072);
    s_init = true;
  }

  k_prep<<<512, 256, 0, stream>>>(w0, w1, w0b, w1b, bn);
  k_p2t <<<dim3(32, 8, 8),  dim3(32, 8), 0, stream>>>(p2, p2t);
  k_p1t <<<dim3(512, 8, 8), dim3(32, 8), 0, stream>>>(p1, xcat);
  k_nn  <<<512, 256, 0, stream>>>(xyz1, xyz2, p2t, xcat);
  k_gemm<<<512, 512, 131072, stream>>>(xcat, w0b, y0, bn + 0,   bn + 256, 512);
  k_bn  <<<1, 256, 0, stream>>>(bn + 0,   bn + 256, g0, be0, bn + 1024, bn + 1280);
  k_z   <<<16384, 256, 0, stream>>>(y0, bn + 1024, bn + 1280, zbuf);
  k_gemm<<<512, 512, 131072, stream>>>(zbuf, w1b, y1, bn + 512, bn + 768, 256);
  k_bn  <<<1, 256, 0, stream>>>(bn + 512, bn + 768, g1, be1, bn + 1536, bn + 1792);
  k_out <<<dim3(256, 4, 8), 256, 0, stream>>>(y1, bn + 1536, bn + 1792, (float*)d_out);
}

// Round 6
// 497.665 us; speedup vs baseline: 1.0920x; 1.0162x over previous
//
#include <hip/hip_runtime.h>
#include <stdint.h>

// Problem constants
#define BB    8
#define NN_   16384
#define SS    1024
#define PP    131072    // BB*NN_
#define CIN   512
#define CMID  256
#define COUT  256

typedef short  bf16x8 __attribute__((ext_vector_type(8)));
typedef float  f32x4  __attribute__((ext_vector_type(4)));
typedef unsigned short u16x8 __attribute__((ext_vector_type(8)));
typedef unsigned int uint_;

__device__ __forceinline__ float bf2f(unsigned short u){
  union { unsigned int i; float f; } v; v.i = ((unsigned int)u) << 16; return v.f;
}
__device__ __forceinline__ unsigned short f2bf(float f){
  union { float f; unsigned int i; } v; v.f = f;
  unsigned int r = (v.i + 0x7fffu + ((v.i >> 16) & 1u)) >> 16;  // RNE
  return (unsigned short)r;
}

// async global->LDS, 16B per lane; LDS dest must be wave-uniform base (+lane*16 implicit)
__device__ __forceinline__ void async_ld16(const void* g, void* l){
  const uint32_t __attribute__((address_space(1)))* gp =
    reinterpret_cast<const uint32_t __attribute__((address_space(1)))*>(reinterpret_cast<uintptr_t>(g));
  uint32_t __attribute__((address_space(3)))* lp =
    reinterpret_cast<uint32_t __attribute__((address_space(3)))*>(reinterpret_cast<uintptr_t>(l));
  __builtin_amdgcn_global_load_lds(gp, lp, 16, 0, 0);
}

// ---------------------------------------------------------------------------
// Prep: weights fp32->bf16, zero BN stats. (conv biases b0/b1 cancel exactly in
// training-mode BN: (y+b) - mean(y+b) == y - mean(y); variance unchanged.)
__global__ void k_prep(const float* __restrict__ w0, const float* __restrict__ w1,
                       unsigned short* __restrict__ w0b, unsigned short* __restrict__ w1b,
                       float* __restrict__ bn)
{
  int idx = blockIdx.x * 256 + threadIdx.x;   // grid 512 -> 131072 threads
  if (idx < 131072) w0b[idx] = f2bf(w0[idx]);
  if (idx < 65536)  w1b[idx] = f2bf(w1[idx]);
  if (idx < 2048)   bn[idx]  = 0.0f;          // stats + params region
}

// ---------------------------------------------------------------------------
// points2 [B][256][S] fp32 -> p2t [B][S][256] fp32 (coalesced gather rows)
__global__ void k_p2t(const float* __restrict__ p2, float* __restrict__ p2t)
{
  __shared__ float t[32][33];
  const int b = blockIdx.z, c0 = blockIdx.y * 32, s0 = blockIdx.x * 32;
  const int tx = threadIdx.x, ty = threadIdx.y;   // (32,8)
#pragma unroll
  for (int r = 0; r < 4; r++)
    t[ty + r*8][tx] = p2[((size_t)b*256 + c0 + ty + r*8) * SS + s0 + tx];
  __syncthreads();
#pragma unroll
  for (int r = 0; r < 4; r++)
    p2t[((size_t)b*SS + s0 + ty + r*8) * 256 + c0 + tx] = t[tx][ty + r*8];
}

// points1 [B][256][N] fp32 -> xcat[p][0:256] bf16  (row stride 512)
__global__ void k_p1t(const float* __restrict__ p1, unsigned short* __restrict__ xcat)
{
  __shared__ float t[32][33];
  const int b = blockIdx.z, c0 = blockIdx.y * 32, n0 = blockIdx.x * 32;
  const int tx = threadIdx.x, ty = threadIdx.y;
#pragma unroll
  for (int r = 0; r < 4; r++)
    t[ty + r*8][tx] = p1[((size_t)b*256 + c0 + ty + r*8) * (size_t)NN_ + n0 + tx];
  __syncthreads();
#pragma unroll
  for (int r = 0; r < 4; r++)
    xcat[((size_t)b*NN_ + n0 + ty + r*8) * 512 + c0 + tx] = f2bf(t[tx][ty + r*8]);
}

// ---------------------------------------------------------------------------
// 3-NN + inverse-distance interp -> xcat[p][256:512] bf16
// R10: distance via d^2 = |p|^2 - 2 q.p + |q|^2 with |p|^2 precomputed into
//      pts[].w (was pad): 3 sub + 3 fma -> 3 fma + 1 add. Key remains d^2
//      (the +|q|^2 keeps bucket quantum relative to d^2, not the shifted h;
//      cancellation error ~1e-7 << quantum ~2e-6, and the fp64 refine
//      recomputes exact distances for the 6 candidates -> selection safe).
// R7: med3 network (float-domain keys), fp64 refine of 6 candidates.
__global__ __launch_bounds__(256) void k_nn(const float* __restrict__ xyz1,
                                            const float* __restrict__ xyz2,
                                            const float* __restrict__ p2t,
                                            unsigned short* __restrict__ xcat)
{
  __shared__ float4 pts[SS];       // 16 KB, broadcast reads
  __shared__ int4   mi[256];       // 4 KB: i0,i1,i2,pad per point
  __shared__ float4 mw[256];       // 4 KB: w0,w1,w2,pad per point
  const int blk = blockIdx.x;                  // 512 blocks
  const int b = blk & 7, nt = blk >> 3;        // XCD-aware: b == XCD id
  const int n0 = nt * 256, tid = threadIdx.x;

  for (int s = tid; s < SS; s += 256) {
    float x = xyz2[((size_t)b*3 + 0) * SS + s];
    float y = xyz2[((size_t)b*3 + 1) * SS + s];
    float z = xyz2[((size_t)b*3 + 2) * SS + s];
    pts[s] = make_float4(x, y, z, fmaf(x, x, fmaf(y, y, z * z)));
  }
  __syncthreads();

  const int n = n0 + tid;
  const float qx = xyz1[((size_t)b*3 + 0) * NN_ + n];
  const float qy = xyz1[((size_t)b*3 + 1) * NN_ + n];
  const float qz = xyz1[((size_t)b*3 + 2) * NN_ + n];
  const float qx2 = -2.0f*qx, qy2 = -2.0f*qy, qz2 = -2.0f*qz;
  const float qq  = fmaf(qx, qx, fmaf(qy, qy, qz * qz));

  // float-domain keys: key = bits((d2 & 0xFFFFFC00) | s); d2 ordering ==
  // float ordering (tiny negative d2 from cancellation still sorts first,
  // which is correct: those are the closest points). init FLT_MAX.
  const float KINIT = __uint_as_float(0x7F7FFFFFu);
  float c0 = KINIT, c1 = KINIT, c2 = KINIT, c3 = KINIT, c4 = KINIT, c5 = KINIT;
#pragma unroll 4
  for (int s = 0; s < SS; s++) {
    float4 p = pts[s];
    float d = fmaf(qx2, p.x, fmaf(qy2, p.y, fmaf(qz2, p.z, p.w))) + qq;
    float key = __uint_as_float((__float_as_uint(d) & 0xFFFFFC00u) | (uint_)s);
    // sorted-insert, all from OLD values: n0=min(c0,key), ni=med3(c_{i-1},ci,key)
    float m0 = fminf(c0, key);
    float m1 = __builtin_amdgcn_fmed3f(c0, c1, key);
    float m2 = __builtin_amdgcn_fmed3f(c1, c2, key);
    float m3 = __builtin_amdgcn_fmed3f(c2, c3, key);
    float m4 = __builtin_amdgcn_fmed3f(c3, c4, key);
    float m5 = __builtin_amdgcn_fmed3f(c4, c5, key);
    c0 = m0; c1 = m1; c2 = m2; c3 = m3; c4 = m4; c5 = m5;
  }

  // fp64 refine: exact distances for the 6 candidates, stable sort, top-3
  const double qxd = (double)qx, qyd = (double)qy, qzd = (double)qz;
  uint_  ks[6] = { __float_as_uint(c0), __float_as_uint(c1), __float_as_uint(c2),
                   __float_as_uint(c3), __float_as_uint(c4), __float_as_uint(c5) };
  int    ii[6];
  double dd[6];
#pragma unroll
  for (int t = 0; t < 6; t++) {
    ii[t] = (int)(ks[t] & 1023u);
    float4 p = pts[ii[t]];
    double dx = qxd - (double)p.x, dy = qyd - (double)p.y, dz = qzd - (double)p.z;
    dd[t] = dx*dx + dy*dy + dz*dz;
  }
#pragma unroll
  for (int a = 1; a < 6; a++)
#pragma unroll
    for (int c = a; c > 0; c--)
      if (dd[c] < dd[c-1]) {
        double td = dd[c]; dd[c] = dd[c-1]; dd[c-1] = td;
        int    ti = ii[c]; ii[c] = ii[c-1]; ii[c-1] = ti;
      }

  double r0 = 1.0/(dd[0] + 1e-8), r1 = 1.0/(dd[1] + 1e-8), r2 = 1.0/(dd[2] + 1e-8);
  double rs = 1.0/(r0 + r1 + r2);
  mi[tid] = make_int4(ii[0], ii[1], ii[2], 0);
  mw[tid] = make_float4((float)(r0*rs), (float)(r1*rs), (float)(r2*rs), 0.0f);
  __syncthreads();

  const int wid = tid >> 6, lane = tid & 63;
  const float* p2tb = p2t + (size_t)b * SS * 256;
  unsigned short* outb = xcat + ((size_t)b*NN_ + n0) * 512 + 256 + lane*4;
#pragma unroll 2
  for (int t = 0; t < 64; t++) {
    int j = wid*64 + t;
    int4   im = mi[j];                 // broadcast ds_read_b128
    float4 wm = mw[j];
    const float4* ra = (const float4*)(p2tb + (size_t)im.x * 256) + lane;
    const float4* rb = (const float4*)(p2tb + (size_t)im.y * 256) + lane;
    const float4* rc = (const float4*)(p2tb + (size_t)im.z * 256) + lane;
    float4 A = *ra, Bv = *rb, Cv = *rc;
    float fx = wm.x*A.x + wm.y*Bv.x + wm.z*Cv.x;
    float fy = wm.x*A.y + wm.y*Bv.y + wm.z*Cv.y;
    float fz = wm.x*A.z + wm.y*Bv.z + wm.z*Cv.z;
    float fw = wm.x*A.w + wm.y*Bv.w + wm.z*Cv.w;
    uint_ lo = (uint_)f2bf(fx) | ((uint_)f2bf(fy) << 16);
    uint_ hi = (uint_)f2bf(fz) | ((uint_)f2bf(fw) << 16);
    uint2 pk; pk.x = lo; pk.y = hi;
    *(uint2*)(outb + (size_t)j * 512) = pk;
  }
}

// ---------------------------------------------------------------------------
// NT GEMM: Y[p][o] = sum_c X[p][c]*W[o][c].  X:[P][K] bf16, W:[256][K] bf16.
// R9 structure: 256x256 tile, 8 waves of 128x64, BK=32, 4 LDS buffers, ONE
//     barrier per K-step, stage(t+3) issue-early, counted vmcnt, setprio.
// R10: template<FUSE_BN>. gemm2 reads RAW y0 and applies BN0+ReLU in-register
//     on the A-frags (k-chunk mapping: lane reads chunk==quad, so af[m]'s 8
//     values are channels t*32+quad*8+j for all m). scale/shift preloaded to
//     a 2KB LDS region at smem+131072; param global loads issued BEFORE the
//     stage loads so the compiler's dep-wait is vmcnt(12), not a full drain.
//     This deletes the k_z kernel (128 MB round trip, ~25 us).
// Epilogue: per-channel sum/sumsq atomics (BN stats) + bf16 store.
template<bool FUSE>
__global__ __launch_bounds__(512, 2) void k_gemm(const unsigned short* __restrict__ X,
                                                 const unsigned short* __restrict__ W,
                                                 unsigned short* __restrict__ Y,
                                                 float* __restrict__ bnsum,
                                                 float* __restrict__ bnsumsq,
                                                 int K,
                                                 const float* __restrict__ zscale,
                                                 const float* __restrict__ zshift)
{
  extern __shared__ char smem[];   // 4 bufs x 32KB: [A 16KB | B 16KB] (+2KB params if FUSE)
  const int tid  = threadIdx.x;
  const int wid  = tid >> 6, lane = tid & 63;
  const int quad = lane >> 4, l16 = lane & 15;
  const int wp = wid >> 2, wo = wid & 3;          // 2 p-waves x 4 o-waves
  const size_t p0 = (size_t)blockIdx.x * 256;
  float* pprm = (float*)(smem + 131072);          // [0:256) scale, [256:512) shift

  f32x4 acc[8][4] = {};   // 128 regs (AGPR side of unified file)

  // --- staging map: per buffer A = 1024 granules of 16B (256 rows x 4 slots)
  const int grow = (wid << 4) | (lane >> 2);
  const int gcol = (((lane & 3) ^ ((lane >> 3) & 3)) << 3);   // elems (0,8,16,24)
  const unsigned short* gA0 = X + (p0 + grow)       * (size_t)K + gcol;
  const unsigned short* gA1 = X + (p0 + grow + 128) * (size_t)K + gcol;
  const unsigned short* gB0 = W + (size_t)(grow)       * K + gcol;
  const unsigned short* gB1 = W + (size_t)(grow + 128) * K + gcol;
  const int ldw = wid << 10;   // wid*1024 bytes (64 granules)

  auto stage = [&](int t) {
    char* base = smem + ((t & 3) << 15);
    const int kk = t << 5;
    async_ld16(gA0 + kk, base + ldw);
    async_ld16(gA1 + kk, base + 8192 + ldw);
    async_ld16(gB0 + kk, base + 16384 + ldw);
    async_ld16(gB1 + kk, base + 16384 + 8192 + ldw);
  };

  // --- frag-read offsets (within a buffer region), swizzled slot
  const int sw   = (quad ^ ((l16 >> 1) & 3)) << 4;
  const int aoff = ((wp << 7) + l16) * 64 + sw;   // + m*1024
  const int boff = ((wo << 6) + l16) * 64 + sw;   // + n*1024

  // param preload: global loads FIRST (older than stage loads -> the ds_write
  // dep-wait is vmcnt(12) and keeps the 12 stage loads in flight)
  float psc = 0.0f, psh = 0.0f;
  if constexpr (FUSE) {
    if (tid < 256) { psc = zscale[tid]; psh = zshift[tid]; }
  }
  const int nt = K >> 5;
  stage(0); stage(1); stage(2);
  if constexpr (FUSE) {
    if (tid < 256) { pprm[tid] = psc; pprm[256 + tid] = psh; }
    asm volatile("s_waitcnt lgkmcnt(0)" ::: "memory");   // params visible
  }
  asm volatile("s_waitcnt vmcnt(8)" ::: "memory");       // buf0 landed (1,2 in flight)
  __builtin_amdgcn_s_barrier();

  for (int t = 0; t < nt; ++t) {
    if (t + 3 < nt) stage(t + 3);      // issue-early; writes buf[(t-1)&3], safe
    const char* buf = smem + ((t & 3) << 15);
    bf16x8 af[8], bfr[4];
#pragma unroll
    for (int m = 0; m < 8; m++) af[m]  = *(const bf16x8*)(buf + aoff + m*1024);
#pragma unroll
    for (int n = 0; n < 4; n++) bfr[n] = *(const bf16x8*)(buf + 16384 + boff + n*1024);
    if constexpr (FUSE) {
      // af[m] channels are t*32 + quad*8 + j (same for all m)
      const float* sp = pprm + (t << 5) + (quad << 3);
      f32x4 sc0 = *(const f32x4*)sp,         sc1 = *(const f32x4*)(sp + 4);
      f32x4 sh0 = *(const f32x4*)(sp + 256), sh1 = *(const f32x4*)(sp + 260);
#pragma unroll
      for (int m = 0; m < 8; m++) {
#pragma unroll
        for (int j = 0; j < 8; j++) {
          float f  = bf2f((unsigned short)af[m][j]);
          float s_ = (j < 4) ? sc0[j] : sc1[j - 4];
          float h_ = (j < 4) ? sh0[j] : sh1[j - 4];
          af[m][j] = (short)f2bf(fmaxf(fmaf(f, s_, h_), 0.0f));
        }
      }
    }
    __builtin_amdgcn_s_setprio(1);
#pragma unroll
    for (int m = 0; m < 8; m++)
#pragma unroll
      for (int n = 0; n < 4; n++)
        acc[m][n] = __builtin_amdgcn_mfma_f32_16x16x32_bf16(af[m], bfr[n], acc[m][n], 0, 0, 0);
    __builtin_amdgcn_s_setprio(0);
    if (t < nt - 1) {
      // wait tile t+1 landed; outstanding beyond it stays in flight
      if (t + 3 < nt)       asm volatile("s_waitcnt vmcnt(8)" ::: "memory");
      else if (t + 3 == nt) asm volatile("s_waitcnt vmcnt(4)" ::: "memory");
      else                  asm volatile("s_waitcnt vmcnt(0)" ::: "memory");
      __builtin_amdgcn_s_barrier();
    }
  }

  // BN stats: lane sums its 32 rows (8m x 4i), reduce across quads, atomic per o
#pragma unroll
  for (int n = 0; n < 4; n++) {
    float s = 0.0f, ss = 0.0f;
#pragma unroll
    for (int m = 0; m < 8; m++)
#pragma unroll
      for (int i = 0; i < 4; i++) { float v = acc[m][n][i]; s += v; ss += v*v; }
    s  += __shfl_xor(s, 16, 64);  s  += __shfl_xor(s, 32, 64);
    ss += __shfl_xor(ss, 16, 64); ss += __shfl_xor(ss, 32, 64);
    if (quad == 0) {
      int o = (wo << 6) + (n << 4) + l16;
      atomicAdd(&bnsum[o], s);
      atomicAdd(&bnsumsq[o], ss);
    }
  }
  // store raw y (bf16). D: row(p)=quad*4+i, col(o)=l16
#pragma unroll
  for (int m = 0; m < 8; m++)
#pragma unroll
    for (int n = 0; n < 4; n++)
#pragma unroll
      for (int i = 0; i < 4; i++) {
        size_t p = p0 + (wp << 7) + (m << 4) + (quad << 2) + i;
        int    o = (wo << 6) + (n << 4) + l16;
        Y[p * 256 + o] = f2bf(acc[m][n][i]);
      }
}

// ---------------------------------------------------------------------------
// BN param: scale = g*rsqrt(var+eps), shift = be - mean*scale
__global__ void k_bn(const float* __restrict__ sum, const float* __restrict__ sumsq,
                     const float* __restrict__ g, const float* __restrict__ be,
                     float* __restrict__ scale, float* __restrict__ shift)
{
  int o = threadIdx.x;
  const float inv = 1.0f / 131072.0f;
  float m  = sum[o] * inv;
  float v  = sumsq[o] * inv - m * m;
  float sc = g[o] * rsqrtf(v + 1e-5f);
  scale[o] = sc;
  shift[o] = be[o] - m * sc;
}

// final: y1[p][o] bf16 -> out[b][o][n] fp32 with BN+relu, LDS transpose
__global__ __launch_bounds__(256) void k_out(const unsigned short* __restrict__ y1,
                                             const float* __restrict__ scale,
                                             const float* __restrict__ shift,
                                             float* __restrict__ out)
{
  __shared__ float t[64][65];
  const int b = blockIdx.z, o0 = blockIdx.y * 64, n0 = blockIdx.x * 64;
  const int tx = threadIdx.x & 15, ty = threadIdx.x >> 4;
  const float4 sc = *(const float4*)(scale + o0 + tx*4);
  const float4 sh = *(const float4*)(shift + o0 + tx*4);
#pragma unroll
  for (int r = 0; r < 4; r++) {
    int nl = ty + r*16;
    const unsigned short* src = y1 + ((size_t)b*NN_ + n0 + nl) * 256 + o0 + tx*4;
    ushort4 v = *(const ushort4*)src;
    t[tx*4+0][nl] = fmaxf(bf2f(v.x) * sc.x + sh.x, 0.0f);
    t[tx*4+1][nl] = fmaxf(bf2f(v.y) * sc.y + sh.y, 0.0f);
    t[tx*4+2][nl] = fmaxf(bf2f(v.z) * sc.z + sh.z, 0.0f);
    t[tx*4+3][nl] = fmaxf(bf2f(v.w) * sc.w + sh.w, 0.0f);
  }
  __syncthreads();
#pragma unroll
  for (int r = 0; r < 4; r++) {
    int ol = ty + r*16;
    float4 o4 = make_float4(t[ol][tx*4+0], t[ol][tx*4+1], t[ol][tx*4+2], t[ol][tx*4+3]);
    *(float4*)(out + ((size_t)b*256 + o0 + ol) * (size_t)NN_ + n0 + tx*4) = o4;
  }
}

// ---------------------------------------------------------------------------
extern "C" void kernel_launch(void* const* d_in, const int* in_sizes, int n_in,
                              void* d_out, int out_size, void* d_ws, size_t ws_size,
                              hipStream_t stream)
{
  const float* xyz1 = (const float*)d_in[0];
  const float* xyz2 = (const float*)d_in[1];
  const float* p1   = (const float*)d_in[2];
  const float* p2   = (const float*)d_in[3];
  const float* w0   = (const float*)d_in[4];
  const float* g0   = (const float*)d_in[6];
  const float* be0  = (const float*)d_in[7];
  const float* w1   = (const float*)d_in[8];
  const float* g1   = (const float*)d_in[10];
  const float* be1  = (const float*)d_in[11];

  // workspace layout (~192.5 MiB):
  //   [0,128Mi)    xcat [P][512] bf16      (y1 reuses [64Mi,128Mi) after gemm1)
  //   [128,192Mi)  y0 [P][256] bf16        (p2t aliases its first 8 MiB; dead before gemm1 writes)
  //   [192Mi,...]  w0b, w1b, bn stats/params
  char* ws = (char*)d_ws;
  unsigned short* xcat = (unsigned short*)(ws);
  unsigned short* y0   = (unsigned short*)(ws + 134217728ull);
  unsigned short* y1   = (unsigned short*)(ws + 67108864ull);
  float*          p2t  = (float*)        (ws + 134217728ull);
  unsigned short* w0b  = (unsigned short*)(ws + 201326592ull);
  unsigned short* w1b  = (unsigned short*)(ws + 201588736ull);
  float*          bn   = (float*)        (ws + 201719808ull);
  // bn: [0]sum0 [256]sumsq0 [512]sum1 [768]sumsq1 [1024]scale0 [1280]shift0 [1536]scale1 [1792]shift1

  static bool s_init = false;
  if (!s_init) {
    hipFuncSetAttribute(reinterpret_cast<const void*>(&k_gemm<false>),
                        hipFuncAttributeMaxDynamicSharedMemorySize, 131072);
    hipFuncSetAttribute(reinterpret_cast<const void*>(&k_gemm<true>),
                        hipFuncAttributeMaxDynamicSharedMemorySize, 133120);
    s_init = true;
  }

  k_prep<<<512, 256, 0, stream>>>(w0, w1, w0b, w1b, bn);
  k_p2t <<<dim3(32, 8, 8),  dim3(32, 8), 0, stream>>>(p2, p2t);
  k_p1t <<<dim3(512, 8, 8), dim3(32, 8), 0, stream>>>(p1, xcat);
  k_nn  <<<512, 256, 0, stream>>>(xyz1, xyz2, p2t, xcat);
  k_gemm<false><<<512, 512, 131072, stream>>>(xcat, w0b, y0, bn + 0, bn + 256, 512,
                                              nullptr, nullptr);
  k_bn  <<<1, 256, 0, stream>>>(bn + 0,   bn + 256, g0, be0, bn + 1024, bn + 1280);
  k_gemm<true><<<512, 512, 133120, stream>>>(y0, w1b, y1, bn + 512, bn + 768, 256,
                                             bn + 1024, bn + 1280);
  k_bn  <<<1, 256, 0, stream>>>(bn + 512, bn + 768, g1, be1, bn + 1536, bn + 1792);
  k_out <<<dim3(256, 4, 8), 256, 0, stream>>>(y1, bn + 1536, bn + 1792, (float*)d_out);
}

// Round 7
// 487.595 us; speedup vs baseline: 1.1146x; 1.0207x over previous
//
#include <hip/hip_runtime.h>
#include <stdint.h>

// Problem constants
#define BB    8
#define NN_   16384
#define SS    1024
#define PP    131072    // BB*NN_
#define CIN   512
#define CMID  256
#define COUT  256

typedef short  bf16x8 __attribute__((ext_vector_type(8)));
typedef float  f32x4  __attribute__((ext_vector_type(4)));
typedef unsigned short u16x8 __attribute__((ext_vector_type(8)));
typedef unsigned int uint_;

__device__ __forceinline__ float bf2f(unsigned short u){
  union { unsigned int i; float f; } v; v.i = ((unsigned int)u) << 16; return v.f;
}
__device__ __forceinline__ unsigned short f2bf(float f){
  union { float f; unsigned int i; } v; v.f = f;
  unsigned int r = (v.i + 0x7fffu + ((v.i >> 16) & 1u)) >> 16;  // RNE
  return (unsigned short)r;
}

// async global->LDS, 16B per lane; LDS dest must be wave-uniform base (+lane*16 implicit)
__device__ __forceinline__ void async_ld16(const void* g, void* l){
  const uint32_t __attribute__((address_space(1)))* gp =
    reinterpret_cast<const uint32_t __attribute__((address_space(1)))*>(reinterpret_cast<uintptr_t>(g));
  uint32_t __attribute__((address_space(3)))* lp =
    reinterpret_cast<uint32_t __attribute__((address_space(3)))*>(reinterpret_cast<uintptr_t>(l));
  __builtin_amdgcn_global_load_lds(gp, lp, 16, 0, 0);
}

// ---------------------------------------------------------------------------
// Prep: weights fp32->bf16, zero BN stats. (conv biases b0/b1 cancel exactly in
// training-mode BN: (y+b) - mean(y+b) == y - mean(y); variance unchanged.)
__global__ void k_prep(const float* __restrict__ w0, const float* __restrict__ w1,
                       unsigned short* __restrict__ w0b, unsigned short* __restrict__ w1b,
                       float* __restrict__ bn)
{
  int idx = blockIdx.x * 256 + threadIdx.x;   // grid 512 -> 131072 threads
  if (idx < 131072) w0b[idx] = f2bf(w0[idx]);
  if (idx < 65536)  w1b[idx] = f2bf(w1[idx]);
  if (idx < 2048)   bn[idx]  = 0.0f;          // stats + params region
}

// ---------------------------------------------------------------------------
// points2 [B][256][S] fp32 -> p2t [B][S][256] fp32 (coalesced gather rows)
__global__ void k_p2t(const float* __restrict__ p2, float* __restrict__ p2t)
{
  __shared__ float t[32][33];
  const int b = blockIdx.z, c0 = blockIdx.y * 32, s0 = blockIdx.x * 32;
  const int tx = threadIdx.x, ty = threadIdx.y;   // (32,8)
#pragma unroll
  for (int r = 0; r < 4; r++)
    t[ty + r*8][tx] = p2[((size_t)b*256 + c0 + ty + r*8) * SS + s0 + tx];
  __syncthreads();
#pragma unroll
  for (int r = 0; r < 4; r++)
    p2t[((size_t)b*SS + s0 + ty + r*8) * 256 + c0 + tx] = t[tx][ty + r*8];
}

// points1 [B][256][N] fp32 -> xcat[p][0:256] bf16  (row stride 512)
__global__ void k_p1t(const float* __restrict__ p1, unsigned short* __restrict__ xcat)
{
  __shared__ float t[32][33];
  const int b = blockIdx.z, c0 = blockIdx.y * 32, n0 = blockIdx.x * 32;
  const int tx = threadIdx.x, ty = threadIdx.y;
#pragma unroll
  for (int r = 0; r < 4; r++)
    t[ty + r*8][tx] = p1[((size_t)b*256 + c0 + ty + r*8) * (size_t)NN_ + n0 + tx];
  __syncthreads();
#pragma unroll
  for (int r = 0; r < 4; r++)
    xcat[((size_t)b*NN_ + n0 + ty + r*8) * 512 + c0 + tx] = f2bf(t[tx][ty + r*8]);
}

// ---------------------------------------------------------------------------
// 3-NN + inverse-distance interp -> xcat[p][256:512] bf16
// R11: split-scan, measured in isolation this time (R8's version was
//      confounded with a gemm regression). Grid 512->1024 blocks; thread
//      (tq, half) scans s in [half*512, half*512+512); halves merged via LDS
//      top-6 union. Merge is exact: every true top-3 key is in its half's
//      top-6, keys unique via index bits -> merged top-6 contains true top-3;
//      fp64 refine unchanged. 2->4 waves/SIMD covers the med3 dep chain and
//      ds_read latency. unroll 8 for deeper MLP.
// R10: d^2 = |p|^2 - 2 q.p + |q|^2, |p|^2 in pts[].w.
// R7:  med3 network (float-domain keys), fp64 refine of 6 candidates.
__global__ __launch_bounds__(256) void k_nn(const float* __restrict__ xyz1,
                                            const float* __restrict__ xyz2,
                                            const float* __restrict__ p2t,
                                            unsigned short* __restrict__ xcat)
{
  __shared__ float4 pts[SS];       // 16 KB, broadcast reads
  __shared__ int4   mi[128];       // i0,i1,i2,pad per point
  __shared__ float4 mw[128];       // w0,w1,w2,pad per point
  __shared__ float  ck[128][6];    // half-1 partial top-6 keys
  const int blk = blockIdx.x;                  // 1024 blocks
  const int b = blk & 7, nt = blk >> 3;        // XCD-aware: b == XCD id
  const int n0 = nt * 128, tid = threadIdx.x;
  const int tq = tid & 127, half = tid >> 7;

  for (int s = tid; s < SS; s += 256) {
    float x = xyz2[((size_t)b*3 + 0) * SS + s];
    float y = xyz2[((size_t)b*3 + 1) * SS + s];
    float z = xyz2[((size_t)b*3 + 2) * SS + s];
    pts[s] = make_float4(x, y, z, fmaf(x, x, fmaf(y, y, z * z)));
  }
  __syncthreads();

  const int n = n0 + tq;
  const float qx = xyz1[((size_t)b*3 + 0) * NN_ + n];
  const float qy = xyz1[((size_t)b*3 + 1) * NN_ + n];
  const float qz = xyz1[((size_t)b*3 + 2) * NN_ + n];
  const float qx2 = -2.0f*qx, qy2 = -2.0f*qy, qz2 = -2.0f*qz;
  const float qq  = fmaf(qx, qx, fmaf(qy, qy, qz * qz));

  // float-domain keys: key = bits((d2 & 0xFFFFFC00) | s); d2 ordering ==
  // float ordering. init FLT_MAX.
  const float KINIT = __uint_as_float(0x7F7FFFFFu);
  float c0 = KINIT, c1 = KINIT, c2 = KINIT, c3 = KINIT, c4 = KINIT, c5 = KINIT;
  const int sbeg = half << 9;
#pragma unroll 8
  for (int s = sbeg; s < sbeg + 512; s++) {
    float4 p = pts[s];
    float d = fmaf(qx2, p.x, fmaf(qy2, p.y, fmaf(qz2, p.z, p.w))) + qq;
    float key = __uint_as_float((__float_as_uint(d) & 0xFFFFFC00u) | (uint_)s);
    // sorted-insert, all from OLD values: n0=min(c0,key), ni=med3(c_{i-1},ci,key)
    float m0 = fminf(c0, key);
    float m1 = __builtin_amdgcn_fmed3f(c0, c1, key);
    float m2 = __builtin_amdgcn_fmed3f(c1, c2, key);
    float m3 = __builtin_amdgcn_fmed3f(c2, c3, key);
    float m4 = __builtin_amdgcn_fmed3f(c3, c4, key);
    float m5 = __builtin_amdgcn_fmed3f(c4, c5, key);
    c0 = m0; c1 = m1; c2 = m2; c3 = m3; c4 = m4; c5 = m5;
  }

  if (half) {
    ck[tq][0] = c0; ck[tq][1] = c1; ck[tq][2] = c2;
    ck[tq][3] = c3; ck[tq][4] = c4; ck[tq][5] = c5;
  }
  __syncthreads();

  if (!half) {
    // merge foreign top-6 into local sorted list
#pragma unroll
    for (int j = 0; j < 6; j++) {
      float key = ck[tq][j];
      float m0 = fminf(c0, key);
      float m1 = __builtin_amdgcn_fmed3f(c0, c1, key);
      float m2 = __builtin_amdgcn_fmed3f(c1, c2, key);
      float m3 = __builtin_amdgcn_fmed3f(c2, c3, key);
      float m4 = __builtin_amdgcn_fmed3f(c3, c4, key);
      float m5 = __builtin_amdgcn_fmed3f(c4, c5, key);
      c0 = m0; c1 = m1; c2 = m2; c3 = m3; c4 = m4; c5 = m5;
    }

    // fp64 refine: exact distances for the 6 candidates, stable sort, top-3
    const double qxd = (double)qx, qyd = (double)qy, qzd = (double)qz;
    uint_  ks[6] = { __float_as_uint(c0), __float_as_uint(c1), __float_as_uint(c2),
                     __float_as_uint(c3), __float_as_uint(c4), __float_as_uint(c5) };
    int    ii[6];
    double dd[6];
#pragma unroll
    for (int t = 0; t < 6; t++) {
      ii[t] = (int)(ks[t] & 1023u);
      float4 p = pts[ii[t]];
      double dx = qxd - (double)p.x, dy = qyd - (double)p.y, dz = qzd - (double)p.z;
      dd[t] = dx*dx + dy*dy + dz*dz;
    }
#pragma unroll
    for (int a = 1; a < 6; a++)
#pragma unroll
      for (int c = a; c > 0; c--)
        if (dd[c] < dd[c-1]) {
          double td = dd[c]; dd[c] = dd[c-1]; dd[c-1] = td;
          int    ti = ii[c]; ii[c] = ii[c-1]; ii[c-1] = ti;
        }

    double r0 = 1.0/(dd[0] + 1e-8), r1 = 1.0/(dd[1] + 1e-8), r2 = 1.0/(dd[2] + 1e-8);
    double rs = 1.0/(r0 + r1 + r2);
    mi[tq] = make_int4(ii[0], ii[1], ii[2], 0);
    mw[tq] = make_float4((float)(r0*rs), (float)(r1*rs), (float)(r2*rs), 0.0f);
  }
  __syncthreads();

  // gather: wave w interpolates points j in [w*32, w*32+32); lane covers 4 ch
  const int wid = tid >> 6, lane = tid & 63;
  const float* p2tb = p2t + (size_t)b * SS * 256;
  unsigned short* outb = xcat + ((size_t)b*NN_ + n0) * 512 + 256 + lane*4;
#pragma unroll 2
  for (int t = 0; t < 32; t++) {
    int j = wid*32 + t;
    int4   im = mi[j];                 // broadcast ds_read_b128
    float4 wm = mw[j];
    const float4* ra = (const float4*)(p2tb + (size_t)im.x * 256) + lane;
    const float4* rb = (const float4*)(p2tb + (size_t)im.y * 256) + lane;
    const float4* rc = (const float4*)(p2tb + (size_t)im.z * 256) + lane;
    float4 A = *ra, Bv = *rb, Cv = *rc;
    float fx = wm.x*A.x + wm.y*Bv.x + wm.z*Cv.x;
    float fy = wm.x*A.y + wm.y*Bv.y + wm.z*Cv.y;
    float fz = wm.x*A.z + wm.y*Bv.z + wm.z*Cv.z;
    float fw = wm.x*A.w + wm.y*Bv.w + wm.z*Cv.w;
    uint_ lo = (uint_)f2bf(fx) | ((uint_)f2bf(fy) << 16);
    uint_ hi = (uint_)f2bf(fz) | ((uint_)f2bf(fw) << 16);
    uint2 pk; pk.x = lo; pk.y = hi;
    *(uint2*)(outb + (size_t)j * 512) = pk;
  }
}

// ---------------------------------------------------------------------------
// NT GEMM: Y[p][o] = sum_c X[p][c]*W[o][c].  X:[P][K] bf16, W:[256][K] bf16.
// R9 structure: 256x256 tile, 8 waves of 128x64, BK=32, 4 LDS buffers, ONE
//     barrier per K-step, stage(t+3) issue-early, counted vmcnt, setprio.
// R10: template<FUSE_BN>. gemm2 reads RAW y0 and applies BN0+ReLU in-register
//     on the A-frags (k-chunk mapping: lane reads chunk==quad, so af[m]'s 8
//     values are channels t*32+quad*8+j for all m). scale/shift preloaded to
//     a 2KB LDS region at smem+131072; param global loads issued BEFORE the
//     stage loads so the compiler's dep-wait keeps stage loads in flight.
//     This deletes the k_z kernel (128 MB round trip, ~25 us).
// Epilogue: per-channel sum/sumsq atomics (BN stats) + bf16 store.
template<bool FUSE>
__global__ __launch_bounds__(512, 2) void k_gemm(const unsigned short* __restrict__ X,
                                                 const unsigned short* __restrict__ W,
                                                 unsigned short* __restrict__ Y,
                                                 float* __restrict__ bnsum,
                                                 float* __restrict__ bnsumsq,
                                                 int K,
                                                 const float* __restrict__ zscale,
                                                 const float* __restrict__ zshift)
{
  extern __shared__ char smem[];   // 4 bufs x 32KB: [A 16KB | B 16KB] (+2KB params if FUSE)
  const int tid  = threadIdx.x;
  const int wid  = tid >> 6, lane = tid & 63;
  const int quad = lane >> 4, l16 = lane & 15;
  const int wp = wid >> 2, wo = wid & 3;          // 2 p-waves x 4 o-waves
  const size_t p0 = (size_t)blockIdx.x * 256;
  float* pprm = (float*)(smem + 131072);          // [0:256) scale, [256:512) shift

  f32x4 acc[8][4] = {};   // 128 regs (AGPR side of unified file)

  // --- staging map: per buffer A = 1024 granules of 16B (256 rows x 4 slots)
  const int grow = (wid << 4) | (lane >> 2);
  const int gcol = (((lane & 3) ^ ((lane >> 3) & 3)) << 3);   // elems (0,8,16,24)
  const unsigned short* gA0 = X + (p0 + grow)       * (size_t)K + gcol;
  const unsigned short* gA1 = X + (p0 + grow + 128) * (size_t)K + gcol;
  const unsigned short* gB0 = W + (size_t)(grow)       * K + gcol;
  const unsigned short* gB1 = W + (size_t)(grow + 128) * K + gcol;
  const int ldw = wid << 10;   // wid*1024 bytes (64 granules)

  auto stage = [&](int t) {
    char* base = smem + ((t & 3) << 15);
    const int kk = t << 5;
    async_ld16(gA0 + kk, base + ldw);
    async_ld16(gA1 + kk, base + 8192 + ldw);
    async_ld16(gB0 + kk, base + 16384 + ldw);
    async_ld16(gB1 + kk, base + 16384 + 8192 + ldw);
  };

  // --- frag-read offsets (within a buffer region), swizzled slot
  const int sw   = (quad ^ ((l16 >> 1) & 3)) << 4;
  const int aoff = ((wp << 7) + l16) * 64 + sw;   // + m*1024
  const int boff = ((wo << 6) + l16) * 64 + sw;   // + n*1024

  // param preload: global loads FIRST (older than stage loads -> the ds_write
  // dep-wait keeps the 12 stage loads in flight)
  float psc = 0.0f, psh = 0.0f;
  if constexpr (FUSE) {
    if (tid < 256) { psc = zscale[tid]; psh = zshift[tid]; }
  }
  const int nt = K >> 5;
  stage(0); stage(1); stage(2);
  if constexpr (FUSE) {
    if (tid < 256) { pprm[tid] = psc; pprm[256 + tid] = psh; }
    asm volatile("s_waitcnt lgkmcnt(0)" ::: "memory");   // params visible
  }
  asm volatile("s_waitcnt vmcnt(8)" ::: "memory");       // buf0 landed (1,2 in flight)
  __builtin_amdgcn_s_barrier();

  for (int t = 0; t < nt; ++t) {
    if (t + 3 < nt) stage(t + 3);      // issue-early; writes buf[(t-1)&3], safe
    const char* buf = smem + ((t & 3) << 15);
    bf16x8 af[8], bfr[4];
#pragma unroll
    for (int m = 0; m < 8; m++) af[m]  = *(const bf16x8*)(buf + aoff + m*1024);
#pragma unroll
    for (int n = 0; n < 4; n++) bfr[n] = *(const bf16x8*)(buf + 16384 + boff + n*1024);
    if constexpr (FUSE) {
      // af[m] channels are t*32 + quad*8 + j (same for all m)
      const float* sp = pprm + (t << 5) + (quad << 3);
      f32x4 sc0 = *(const f32x4*)sp,         sc1 = *(const f32x4*)(sp + 4);
      f32x4 sh0 = *(const f32x4*)(sp + 256), sh1 = *(const f32x4*)(sp + 260);
#pragma unroll
      for (int m = 0; m < 8; m++) {
#pragma unroll
        for (int j = 0; j < 8; j++) {
          float f  = bf2f((unsigned short)af[m][j]);
          float s_ = (j < 4) ? sc0[j] : sc1[j - 4];
          float h_ = (j < 4) ? sh0[j] : sh1[j - 4];
          af[m][j] = (short)f2bf(fmaxf(fmaf(f, s_, h_), 0.0f));
        }
      }
    }
    __builtin_amdgcn_s_setprio(1);
#pragma unroll
    for (int m = 0; m < 8; m++)
#pragma unroll
      for (int n = 0; n < 4; n++)
        acc[m][n] = __builtin_amdgcn_mfma_f32_16x16x32_bf16(af[m], bfr[n], acc[m][n], 0, 0, 0);
    __builtin_amdgcn_s_setprio(0);
    if (t < nt - 1) {
      // wait tile t+1 landed; outstanding beyond it stays in flight
      if (t + 3 < nt)       asm volatile("s_waitcnt vmcnt(8)" ::: "memory");
      else if (t + 3 == nt) asm volatile("s_waitcnt vmcnt(4)" ::: "memory");
      else                  asm volatile("s_waitcnt vmcnt(0)" ::: "memory");
      __builtin_amdgcn_s_barrier();
    }
  }

  // BN stats: lane sums its 32 rows (8m x 4i), reduce across quads, atomic per o
#pragma unroll
  for (int n = 0; n < 4; n++) {
    float s = 0.0f, ss = 0.0f;
#pragma unroll
    for (int m = 0; m < 8; m++)
#pragma unroll
      for (int i = 0; i < 4; i++) { float v = acc[m][n][i]; s += v; ss += v*v; }
    s  += __shfl_xor(s, 16, 64);  s  += __shfl_xor(s, 32, 64);
    ss += __shfl_xor(ss, 16, 64); ss += __shfl_xor(ss, 32, 64);
    if (quad == 0) {
      int o = (wo << 6) + (n << 4) + l16;
      atomicAdd(&bnsum[o], s);
      atomicAdd(&bnsumsq[o], ss);
    }
  }
  // store raw y (bf16). D: row(p)=quad*4+i, col(o)=l16
#pragma unroll
  for (int m = 0; m < 8; m++)
#pragma unroll
    for (int n = 0; n < 4; n++)
#pragma unroll
      for (int i = 0; i < 4; i++) {
        size_t p = p0 + (wp << 7) + (m << 4) + (quad << 2) + i;
        int    o = (wo << 6) + (n << 4) + l16;
        Y[p * 256 + o] = f2bf(acc[m][n][i]);
      }
}

// ---------------------------------------------------------------------------
// BN param: scale = g*rsqrt(var+eps), shift = be - mean*scale
__global__ void k_bn(const float* __restrict__ sum, const float* __restrict__ sumsq,
                     const float* __restrict__ g, const float* __restrict__ be,
                     float* __restrict__ scale, float* __restrict__ shift)
{
  int o = threadIdx.x;
  const float inv = 1.0f / 131072.0f;
  float m  = sum[o] * inv;
  float v  = sumsq[o] * inv - m * m;
  float sc = g[o] * rsqrtf(v + 1e-5f);
  scale[o] = sc;
  shift[o] = be[o] - m * sc;
}

// final: y1[p][o] bf16 -> out[b][o][n] fp32 with BN+relu, LDS transpose
__global__ __launch_bounds__(256) void k_out(const unsigned short* __restrict__ y1,
                                             const float* __restrict__ scale,
                                             const float* __restrict__ shift,
                                             float* __restrict__ out)
{
  __shared__ float t[64][65];
  const int b = blockIdx.z, o0 = blockIdx.y * 64, n0 = blockIdx.x * 64;
  const int tx = threadIdx.x & 15, ty = threadIdx.x >> 4;
  const float4 sc = *(const float4*)(scale + o0 + tx*4);
  const float4 sh = *(const float4*)(shift + o0 + tx*4);
#pragma unroll
  for (int r = 0; r < 4; r++) {
    int nl = ty + r*16;
    const unsigned short* src = y1 + ((size_t)b*NN_ + n0 + nl) * 256 + o0 + tx*4;
    ushort4 v = *(const ushort4*)src;
    t[tx*4+0][nl] = fmaxf(bf2f(v.x) * sc.x + sh.x, 0.0f);
    t[tx*4+1][nl] = fmaxf(bf2f(v.y) * sc.y + sh.y, 0.0f);
    t[tx*4+2][nl] = fmaxf(bf2f(v.z) * sc.z + sh.z, 0.0f);
    t[tx*4+3][nl] = fmaxf(bf2f(v.w) * sc.w + sh.w, 0.0f);
  }
  __syncthreads();
#pragma unroll
  for (int r = 0; r < 4; r++) {
    int ol = ty + r*16;
    float4 o4 = make_float4(t[ol][tx*4+0], t[ol][tx*4+1], t[ol][tx*4+2], t[ol][tx*4+3]);
    *(float4*)(out + ((size_t)b*256 + o0 + ol) * (size_t)NN_ + n0 + tx*4) = o4;
  }
}

// ---------------------------------------------------------------------------
extern "C" void kernel_launch(void* const* d_in, const int* in_sizes, int n_in,
                              void* d_out, int out_size, void* d_ws, size_t ws_size,
                              hipStream_t stream)
{
  const float* xyz1 = (const float*)d_in[0];
  const float* xyz2 = (const float*)d_in[1];
  const float* p1   = (const float*)d_in[2];
  const float* p2   = (const float*)d_in[3];
  const float* w0   = (const float*)d_in[4];
  const float* g0   = (const float*)d_in[6];
  const float* be0  = (const float*)d_in[7];
  const float* w1   = (const float*)d_in[8];
  const float* g1   = (const float*)d_in[10];
  const float* be1  = (const float*)d_in[11];

  // workspace layout (~192.5 MiB):
  //   [0,128Mi)    xcat [P][512] bf16      (y1 reuses [64Mi,128Mi) after gemm1)
  //   [128,192Mi)  y0 [P][256] bf16        (p2t aliases its first 8 MiB; dead before gemm1 writes)
  //   [192Mi,...]  w0b, w1b, bn stats/params
  char* ws = (char*)d_ws;
  unsigned short* xcat = (unsigned short*)(ws);
  unsigned short* y0   = (unsigned short*)(ws + 134217728ull);
  unsigned short* y1   = (unsigned short*)(ws + 67108864ull);
  float*          p2t  = (float*)        (ws + 134217728ull);
  unsigned short* w0b  = (unsigned short*)(ws + 201326592ull);
  unsigned short* w1b  = (unsigned short*)(ws + 201588736ull);
  float*          bn   = (float*)        (ws + 201719808ull);
  // bn: [0]sum0 [256]sumsq0 [512]sum1 [768]sumsq1 [1024]scale0 [1280]shift0 [1536]scale1 [1792]shift1

  static bool s_init = false;
  if (!s_init) {
    hipFuncSetAttribute(reinterpret_cast<const void*>(&k_gemm<false>),
                        hipFuncAttributeMaxDynamicSharedMemorySize, 131072);
    hipFuncSetAttribute(reinterpret_cast<const void*>(&k_gemm<true>),
                        hipFuncAttributeMaxDynamicSharedMemorySize, 133120);
    s_init = true;
  }

  k_prep<<<512, 256, 0, stream>>>(w0, w1, w0b, w1b, bn);
  k_p2t <<<dim3(32, 8, 8),  dim3(32, 8), 0, stream>>>(p2, p2t);
  k_p1t <<<dim3(512, 8, 8), dim3(32, 8), 0, stream>>>(p1, xcat);
  k_nn  <<<1024, 256, 0, stream>>>(xyz1, xyz2, p2t, xcat);
  k_gemm<false><<<512, 512, 131072, stream>>>(xcat, w0b, y0, bn + 0, bn + 256, 512,
                                              nullptr, nullptr);
  k_bn  <<<1, 256, 0, stream>>>(bn + 0,   bn + 256, g0, be0, bn + 1024, bn + 1280);
  k_gemm<true><<<512, 512, 133120, stream>>>(y0, w1b, y1, bn + 512, bn + 768, 256,
                                             bn + 1024, bn + 1280);
  k_bn  <<<1, 256, 0, stream>>>(bn + 512, bn + 768, g1, be1, bn + 1536, bn + 1792);
  k_out <<<dim3(256, 4, 8), 256, 0, stream>>>(y1, bn + 1536, bn + 1792, (float*)d_out);
}